// Round 2
// baseline (277.055 us; speedup 1.0000x reference)
//
#include <hip/hip_runtime.h>
#include <math.h>

// InputSequenceNormalization: x[B,F,T] fp32, lengths[B] fp32.
// n_b = round(lengths[b]*T); per (b,f) row: mean/std over first n_b frames
// (std unbiased ddof=1, clamped at 1e-10), normalize ALL T frames.
//
// Persistent-block 2-row register pipeline: BLOCK=512 (8 waves), VPT=4
// float4/row/thread, two row buffers va/vb (32 data VGPRs). Grid =
// rows/5 = 1024 blocks = exactly 4 blocks/CU at 32 waves/CU
// (__launch_bounds__(512,8) pins VGPR<=64). Each block processes 5 rows;
// row k+1's loads are issued BEFORE row k's reduce barrier, so the HBM
// queue stays full through the vmcnt-drain + reduce + store phase that
// previously left ~12 us of synchronized bubbles (20 block-generations
// x ~0.6 us). Loop fully unrolled so va/vb selection is compile-time
// (runtime-indexed register arrays would spill to scratch).
// var = (ss - s^2/n)/(n-1); fp32 error ~1e-5, threshold 0.109.
// Nontemporal load/store: x read once, out never re-read -> keep L2 clean.

#define ROW_T 8000
#define TV (ROW_T / 4)          // 2000 float4 per row
#define BLOCK 512
#define WAVES (BLOCK / 64)      // 8
#define VPT 4                   // ceil(2000/512) = 4 float4 per thread
#define RPB 5                   // rows per persistent block (5120/5 = 1024 blocks)
#define EPS 1e-10f

typedef float v4f __attribute__((ext_vector_type(4)));

__device__ __forceinline__ void load_row(v4f (&v)[VPT],
                                         const v4f* __restrict__ xr, int tid) {
    #pragma unroll
    for (int it = 0; it < VPT; ++it) {
        const int idx = tid + it * BLOCK;
        if (idx < TV) v[it] = __builtin_nontemporal_load(&xr[idx]);
    }
}

__global__ __launch_bounds__(BLOCK, 8) void isn_kernel(
        const float* __restrict__ x,
        const float* __restrict__ lengths,
        float* __restrict__ out,
        int F, int rows) {
    __shared__ float2 lds[WAVES];
    const int tid = threadIdx.x;
    const int base = blockIdx.x * RPB;

    v4f va[VPT], vb[VPT];
    if (base < rows)
        load_row(va, (const v4f*)(x + (size_t)base * ROW_T), tid);

    #pragma unroll
    for (int k = 0; k < RPB; ++k) {
        const int row = base + k;
        if (row >= rows) break;
        v4f (&v)[VPT]  = (k & 1) ? vb : va;   // compile-time after unroll
        v4f (&vn)[VPT] = (k & 1) ? va : vb;

        const int b = row / F;
        const int n = (int)rintf(lengths[b] * (float)ROW_T);
        const float nf = (float)n;

        // ---- masked sum + sumsq (compiler waits vmcnt on v here) ----
        float s = 0.0f, ss = 0.0f;
        #pragma unroll
        for (int it = 0; it < VPT; ++it) {
            const int bidx = (tid + it * BLOCK) * 4;
            if (bidx < ROW_T) {
                #pragma unroll
                for (int j = 0; j < 4; ++j) {
                    const float xv = (bidx + j < n) ? v[it][j] : 0.0f;
                    s += xv;
                    ss = fmaf(xv, xv, ss);
                }
            }
        }

        // ---- prefetch next row: in flight across the reduce + store ----
        if (k + 1 < RPB && row + 1 < rows)
            load_row(vn, (const v4f*)(x + (size_t)(row + 1) * ROW_T), tid);

        // ---- block reduction of (s, ss): 64-lane shuffle + 8-wave LDS ----
        #pragma unroll
        for (int off = 32; off > 0; off >>= 1) {
            s  += __shfl_down(s, off, 64);
            ss += __shfl_down(ss, off, 64);
        }
        const int wave = tid >> 6;
        const int lane = tid & 63;
        if (k) __syncthreads();   // lds reuse: prior iter's reads must finish
        if (lane == 0) lds[wave] = make_float2(s, ss);
        __syncthreads();
        float rs = 0.0f, rss = 0.0f;
        #pragma unroll
        for (int i = 0; i < WAVES; ++i) { rs += lds[i].x; rss += lds[i].y; }

        const float mean = rs / nf;
        const float var = (rss - rs * rs / nf) / (nf - 1.0f);
        const float inv = 1.0f / fmaxf(sqrtf(var), EPS);

        // ---- normalize ALL frames from registers, nontemporal store ----
        v4f* __restrict__ outr = (v4f*)(out + (size_t)row * ROW_T);
        #pragma unroll
        for (int it = 0; it < VPT; ++it) {
            const int idx = tid + it * BLOCK;
            if (idx < TV) {
                v4f o;
                #pragma unroll
                for (int j = 0; j < 4; ++j)
                    o[j] = (v[it][j] - mean) * inv;
                __builtin_nontemporal_store(o, &outr[idx]);
            }
        }
    }
}

extern "C" void kernel_launch(void* const* d_in, const int* in_sizes, int n_in,
                              void* d_out, int out_size, void* d_ws, size_t ws_size,
                              hipStream_t stream) {
    const float* x = (const float*)d_in[0];
    const float* lengths = (const float*)d_in[1];
    float* out = (float*)d_out;

    const int B = in_sizes[1];                     // 64
    const int F = in_sizes[0] / (B * ROW_T);       // 80
    const int rows = B * F;                        // 5120
    const int grid = (rows + RPB - 1) / RPB;       // 1024 blocks = 4/CU

    isn_kernel<<<grid, BLOCK, 0, stream>>>(x, lengths, out, F, rows);
}

// Round 3
// 271.349 us; speedup vs baseline: 1.0210x; 1.0210x over previous
//
#include <hip/hip_runtime.h>
#include <math.h>

// InputSequenceNormalization: x[B,F,T] fp32, lengths[B] fp32.
// n_b = round(lengths[b]*T); per (b,f) row: mean/std over first n_b frames
// (std unbiased ddof=1, clamped at 1e-10), normalize ALL T frames.
//
// ONE WAVE PER ROW — zero cross-wave coupling. Each 64-lane wave holds its
// entire 8000-float row in registers: 31 float4 + 1 scalar per lane
// (~140 VGPR -> 3 waves/SIMD, 12 waves/CU). All 32 row-loads issue
// back-to-back (32 KB MLP in flight per wave, ~384 KB/CU >> the ~9 KB
// needed to cover 900-cycle HBM latency), the (sum,sumsq) reduce is
// 6 __shfl_xor butterflies — no LDS, no __syncthreads, no 8-wave convoy
// draining vmcnt together (the structural stall of the block-per-row
// versions). Stores are fire-and-forget.
// var = (ss - s^2/n)/(n-1); fp32 error ~1e-5, threshold 0.109.
// Nontemporal load/store: x read once, out never re-read -> keep L2 clean.

#define ROW_T 8000
#define TV (ROW_T / 4)          // 2000 float4 per row
#define BLOCK 256
#define WPB (BLOCK / 64)        // 4 waves = 4 rows per block
#define NV 31                   // full float4 iters per lane (31*64=1984 float4)
#define TAIL_BASE 7936          // 1984*4; remaining 64 floats, 1/lane
#define EPS 1e-10f

typedef float v4f __attribute__((ext_vector_type(4)));

__global__ __launch_bounds__(BLOCK, 2) void isn_kernel(
        const float* __restrict__ x,
        const float* __restrict__ lengths,
        float* __restrict__ out,
        int F, int rows) {
    const int lane = threadIdx.x & 63;
    const int wave = threadIdx.x >> 6;
    const int row = blockIdx.x * WPB + wave;
    if (row >= rows) return;

    const float* __restrict__ xrow = x + (size_t)row * ROW_T;
    const v4f* __restrict__ xr4 = (const v4f*)xrow;

    // valid frame count (jnp.round == rintf: half-to-even); wave-uniform
    const int b = row / F;
    const int n = (int)rintf(lengths[b] * (float)ROW_T);
    const float nf = (float)n;

    // ---- load entire row into registers: 31 float4 + 1 scalar per lane ----
    v4f v[NV];
    #pragma unroll
    for (int i = 0; i < NV; ++i)
        v[i] = __builtin_nontemporal_load(&xr4[i * 64 + lane]);
    const float vt = __builtin_nontemporal_load(&xrow[TAIL_BASE + lane]);

    // ---- masked sum + sumsq (lane-local) ----
    float s = 0.0f, ss = 0.0f;
    #pragma unroll
    for (int i = 0; i < NV; ++i) {
        const int base = (i * 64 + lane) * 4;
        #pragma unroll
        for (int j = 0; j < 4; ++j) {
            const float xv = (base + j < n) ? v[i][j] : 0.0f;
            s += xv;
            ss = fmaf(xv, xv, ss);
        }
    }
    {
        const float xv = (TAIL_BASE + lane < n) ? vt : 0.0f;
        s += xv;
        ss = fmaf(xv, xv, ss);
    }

    // ---- 64-lane butterfly reduce: every lane ends with the totals ----
    #pragma unroll
    for (int off = 1; off < 64; off <<= 1) {
        s  += __shfl_xor(s, off, 64);
        ss += __shfl_xor(ss, off, 64);
    }

    const float mean = s / nf;
    const float var = (ss - s * s / nf) / (nf - 1.0f);
    const float inv = 1.0f / fmaxf(sqrtf(var), EPS);

    // ---- normalize ALL frames from registers, nontemporal store ----
    float* __restrict__ orow = out + (size_t)row * ROW_T;
    v4f* __restrict__ or4 = (v4f*)orow;
    #pragma unroll
    for (int i = 0; i < NV; ++i) {
        v4f o;
        #pragma unroll
        for (int j = 0; j < 4; ++j)
            o[j] = (v[i][j] - mean) * inv;
        __builtin_nontemporal_store(o, &or4[i * 64 + lane]);
    }
    __builtin_nontemporal_store((vt - mean) * inv, &orow[TAIL_BASE + lane]);
}

extern "C" void kernel_launch(void* const* d_in, const int* in_sizes, int n_in,
                              void* d_out, int out_size, void* d_ws, size_t ws_size,
                              hipStream_t stream) {
    const float* x = (const float*)d_in[0];
    const float* lengths = (const float*)d_in[1];
    float* out = (float*)d_out;

    const int B = in_sizes[1];                     // 64
    const int F = in_sizes[0] / (B * ROW_T);       // 80
    const int rows = B * F;                        // 5120
    const int grid = (rows + WPB - 1) / WPB;       // 1280 blocks

    isn_kernel<<<grid, BLOCK, 0, stream>>>(x, lengths, out, F, rows);
}